// Round 6
// baseline (487.308 us; speedup 1.0000x reference)
//
#include <hip/hip_runtime.h>

namespace {
constexpr int kL    = 2048;
constexpr int kV    = 25;
constexpr int kTL   = 8;
constexpr int kXsC  = kL * kV;          // 51200
constexpr long kXsN = 64L * kXsC;
constexpr long kSXn   = 64L * kL * 32;          // SXg per-n stride (ushorts)
constexpr long kSXtot = 16L * kSXn;             // 67,108,864 ushorts
constexpr size_t kWOffB = (size_t)kSXtot * 2;   // weight area byte offset (134,217,728)
constexpr size_t kWBytes = 37120;               // weight area size

typedef __attribute__((ext_vector_type(8))) short  bf16x8;
typedef __attribute__((ext_vector_type(4))) float  f32x4;
typedef __attribute__((ext_vector_type(4))) unsigned short us4;

__device__ __forceinline__ unsigned short f2b(float f) {
  union { float f; unsigned u; } x; x.f = f;
  unsigned r = x.u + 0x7FFF + ((x.u >> 16) & 1);
  return (unsigned short)(r >> 16);
}
}

// ws weight-area layout (ushort offsets from its base):
//  [0, 12288)      stage-2 A-frags bf16[4 mt][6 ksg][64 lane][8]   (W[c][k=p*64+ci])
//  [12288, 15360)  stage-1 B-frags bf16[3 p][2 wt][64 lane][8]     (A[p][v][w], 0-pad)
//  byte 30720      bias2 fp32[64][25]
__global__ void stgcn_pre(const float* __restrict__ A,
                          const float* __restrict__ cw,
                          const float* __restrict__ cb,
                          unsigned short* __restrict__ wsu) {
  int t = threadIdx.x;
  for (int i = t; i < 4 * 6 * 64 * 8; i += 256) {
    int j = i & 7, lane = (i >> 3) & 63;
    int rem = i >> 9;              // 0..23
    int ksg = rem % 6, mt = rem / 6;
    int c = 16 * mt + (lane & 15);
    int k = 32 * ksg + (lane >> 4) * 8 + j;
    int p = k >> 6, ci = k & 63;
    wsu[i] = f2b(cw[(p * 64 + c) * 64 + ci]);
  }
  for (int i = t; i < 3 * 2 * 64 * 8; i += 256) {
    int j = i & 7, lane = (i >> 3) & 63, wt = (i >> 9) & 1, p = i >> 10;
    int w = 16 * wt + (lane & 15);
    int v = (lane >> 4) * 8 + j;
    float val = (v < kV && w < kV) ? A[(p * kV + v) * kV + w] : 0.f;
    wsu[12288 + i] = f2b(val);
  }
  float* bias2 = (float*)((char*)wsu + 30720);
  for (int i = t; i < 64 * kV; i += 256) {
    int c = i / kV, w = i % kV;
    float s = 0.f;
    for (int p = 0; p < 3; ++p) {
      float as = 0.f;
      for (int v = 0; v < kV; ++v) as += A[(p * kV + v) * kV + w];
      s += cb[p * 64 + c] * as;
    }
    bias2[i] = s;
  }
}

// ---- Kernel A: 9-tap causal window sum, x fp32 -> SXg bf16 [n][ci][l][v32] ----
__global__ __launch_bounds__(256)
void stgcn_winsum(const float* __restrict__ x, unsigned short* __restrict__ sxg) {
  const int plane = blockIdx.x;          // n*64 + ci
  const int t  = threadIdx.x;
  const int q  = t & 7;                  // v-quad
  const int ls = t >> 3;                 // l-slice 0..31 (64 l's each)
  const float* px = x + (long)plane * kXsC;
  unsigned short* po = sxg + (long)plane * (kL * 32);
  const int L0 = ls * 64;

  if (q == 7) {                          // cols 28..31 are always zero
    uint2 z = {0u, 0u};
    for (int l = L0; l < L0 + 64; ++l) *(uint2*)&po[l * 32 + 28] = z;
    return;
  }
  const int col = 4 * q;
  const bool full = (q < 6);             // q==6: only v=24 valid (cols 25..27 stay 0)
  float a0 = 0.f, a1 = 0.f, a2 = 0.f, a3 = 0.f;
  if (L0) {
    #pragma unroll
    for (int m = 0; m < 8; ++m) {
      const float* r = px + (long)(L0 - 8 + m) * kV + col;
      a0 += r[0]; if (full) { a1 += r[1]; a2 += r[2]; a3 += r[3]; }
    }
  }
  #pragma unroll 4
  for (int l = L0; l < L0 + 64; ++l) {
    const float* r = px + (long)l * kV + col;
    a0 += r[0]; if (full) { a1 += r[1]; a2 += r[2]; a3 += r[3]; }
    uint2 o;
    o.x = (unsigned)f2b(a0) | ((unsigned)f2b(a1) << 16);
    o.y = (unsigned)f2b(a2) | ((unsigned)f2b(a3) << 16);
    *(uint2*)&po[l * 32 + col] = o;
    if (l >= 8) {
      const float* s = px + (long)(l - 8) * kV + col;
      a0 -= s[0]; if (full) { a1 -= s[1]; a2 -= s[2]; a3 -= s[3]; }
    }
  }
}

// ---- Kernel B: fragments from SXg -> stage1 MFMA -> sYs -> stage2 MFMA -> out ----
__global__ __launch_bounds__(512, 6)
void stgcn_mm(const float* __restrict__ x,
              const unsigned short* __restrict__ sxg,
              const unsigned short* __restrict__ wsu,
              float* __restrict__ out) {
  __shared__ unsigned short sYs[208 * 72];   // Y bf16 [nidx 208][ci pad72]

  const int t   = threadIdx.x;
  const int lam = t & 63;
  const int wid = t >> 6;               // 0..7
  const int h   = lam >> 4;
  const int r16 = lam & 15;
  const int l0  = blockIdx.x * kTL;
  const float* xn = x + (long)blockIdx.y * kXsN;
  float* outn     = out + (long)blockIdx.y * kXsN;
  const float* bias2 = (const float*)((const char*)wsu + 30720);
  const unsigned short* sxn = sxg + (long)blockIdx.y * kSXn;

  // zero sYs pad rows 200..207 (ordered before stage2 by the stage1 barrier)
  for (int i = t; i < 8 * 72; i += 512) sYs[200 * 72 + i] = 0;

  // A-fragments straight from global (m = ci*8+dl mapping, as R3/R5)
  bf16x8 af[4];
  #pragma unroll
  for (int i = 0; i < 4; ++i) {
    const int m  = 16 * (wid * 4 + i) + r16;
    const int ci = m >> 3, dl = m & 7;
    af[i] = *(const bf16x8*)&sxn[((long)ci * kL + l0 + dl) * 32 + 8 * h];
  }

  f32x4 acc[7];
  #pragma unroll
  for (int nt = 0; nt < 7; ++nt) acc[nt] = (f32x4){0.f, 0.f, 0.f, 0.f};

  const int nh  = wid >> 2;       // stage2: n-half
  const int mt2 = wid & 3;        // stage2: c-tile
  const int ntb = nh ? 7 : 0;

  for (int p = 0; p < 3; ++p) {
    // stage 1: Y[nidx=(dl*25+w)][ci] = sum_v SX[(ci,dl)][v] * A[p][v][w]
    #pragma unroll
    for (int wt = 0; wt < 2; ++wt) {
      bf16x8 bf = *(const bf16x8*)&wsu[12288 + ((p * 2 + wt) * 64 + lam) * 8];
      const int w = 16 * wt + r16;
      const bool wok = (w < kV);
      #pragma unroll
      for (int i = 0; i < 4; ++i) {
        const int mt = wid * 4 + i;
        f32x4 c0 = {0.f, 0.f, 0.f, 0.f};
        c0 = __builtin_amdgcn_mfma_f32_16x16x32_bf16(af[i], bf, c0, 0, 0, 0);
        if (wok) {
          const int mb = 16 * mt + 4 * h;
          const int cw_ = mb >> 3, dl0 = mb & 7;
          #pragma unroll
          for (int r = 0; r < 4; ++r)
            sYs[((dl0 + r) * kV + w) * 72 + cw_] = f2b(c0[r]);
        }
      }
    }
    __syncthreads();

    // stage 2: es[c][nidx] += sum_ci W[c][p*64+ci] * Y[nidx][ci]
    #pragma unroll
    for (int ksl = 0; ksl < 2; ++ksl) {
      bf16x8 wf = *(const bf16x8*)&wsu[((mt2 * 6 + p * 2 + ksl) * 64 + lam) * 8];
      #pragma unroll
      for (int nt = 0; nt < 7; ++nt) {
        if (nh == 0 || nt < 6) {
          bf16x8 yf = *(const bf16x8*)&sYs[(16 * (ntb + nt) + r16) * 72 + 32 * ksl + 8 * h];
          acc[nt] = __builtin_amdgcn_mfma_f32_16x16x32_bf16(wf, yf, acc[nt], 0, 0, 0);
        }
      }
    }
    if (p < 2) __syncthreads();
  }

  // Epilogue: + cnt*bias2 + residual, ReLU, store
  const int cb4 = 16 * mt2 + 4 * h;
  #pragma unroll
  for (int nt = 0; nt < 7; ++nt) {
    if (nh == 0 || nt < 6) {
      int nidx = 16 * (ntb + nt) + r16;
      if (nidx < 200) {
        int dl = nidx / 25, wv = nidx - 25 * dl;
        float cnt = l0 ? 9.f : (float)(dl + 1);
        long base = (long)(l0 + dl) * kV + wv;
        #pragma unroll
        for (int r = 0; r < 4; ++r) {
          int c = cb4 + r;
          float val = acc[nt][r] + cnt * bias2[c * kV + wv] + xn[(long)c * kXsC + base];
          outn[(long)c * kXsC + base] = fmaxf(val, 0.f);
        }
      }
    }
  }
}

// ---- Fallback: R5 fused kernel (proven), used only if ws_size is too small ----
__global__ __launch_bounds__(512, 6)
void stgcn_fused(const float* __restrict__ x,
                 const unsigned short* __restrict__ wsu,
                 float* __restrict__ out) {
  __shared__ unsigned short sBuf[512 * 40];
  const int t   = threadIdx.x;
  const int lam = t & 63;
  const int wid = t >> 6;
  const int h   = lam >> 4;
  const int r16 = lam & 15;
  const int l0  = blockIdx.x * kTL;
  const float* xn = x + (long)blockIdx.y * kXsN;
  float* outn     = out + (long)blockIdx.y * kXsN;
  const float* bias2 = (const float*)((const char*)wsu + 30720);

  {
    const int ci = t >> 3, q = t & 7;
    const int rowb = ci * 8 * 40;
    if (q == 7) {
      const int c4 = ((3 ^ (ci & 3)) << 3) | 4;
      us4 z = {0, 0, 0, 0};
      #pragma unroll
      for (int dl = 0; dl < 8; ++dl) *(us4*)&sBuf[rowb + dl * 40 + c4] = z;
    } else {
      const int colL = 4 * q;
      const int c4 = (((colL >> 3) ^ (ci & 3)) << 3) | (colL & 7);
      const float* xr = xn + (long)ci * kXsC + (long)(l0 - 8) * kV + colL;
      const bool full = (q < 6);
      float a0 = 0.f, a1 = 0.f, a2 = 0.f, a3 = 0.f;
      if (l0) {
        #pragma unroll
        for (int j = 0; j < 9; ++j) {
          const float* r = xr + j * kV;
          a0 += r[0];
          if (full) { a1 += r[1]; a2 += r[2]; a3 += r[3]; }
        }
      } else {
        const float* r = xr + 8 * kV;
        a0 = r[0];
        if (full) { a1 = r[1]; a2 = r[2]; a3 = r[3]; }
      }
      #pragma unroll
      for (int dl = 0; dl < 8; ++dl) {
        us4 o = { f2b(a0), f2b(a1), f2b(a2), f2b(a3) };
        *(us4*)&sBuf[rowb + dl * 40 + c4] = o;
        if (dl < 7) {
          const float* pn = xr + (dl + 9) * kV;
          a0 += pn[0];
          if (full) { a1 += pn[1]; a2 += pn[2]; a3 += pn[3]; }
          if (l0) {
            const float* po = xr + dl * kV;
            a0 -= po[0];
            if (full) { a1 -= po[1]; a2 -= po[2]; a3 -= po[3]; }
          }
        }
      }
    }
  }
  __syncthreads();

  bf16x8 af[4];
  #pragma unroll
  for (int i = 0; i < 4; ++i) {
    const int mt = wid * 4 + i;
    const int m  = 16 * mt + r16;
    const int cia = m >> 3;
    af[i] = *(const bf16x8*)&sBuf[m * 40 + ((h ^ (cia & 3)) << 3)];
  }
  __syncthreads();

  for (int i = t; i < 8 * 72; i += 512) sBuf[200 * 72 + i] = 0;

  f32x4 acc[7];
  #pragma unroll
  for (int nt = 0; nt < 7; ++nt) acc[nt] = (f32x4){0.f, 0.f, 0.f, 0.f};

  const int nh  = wid >> 2;
  const int mt2 = wid & 3;
  const int ntb = nh ? 7 : 0;

  for (int p = 0; p < 3; ++p) {
    #pragma unroll
    for (int wt = 0; wt < 2; ++wt) {
      bf16x8 bf = *(const bf16x8*)&wsu[12288 + ((p * 2 + wt) * 64 + lam) * 8];
      const int w = 16 * wt + r16;
      const bool wok = (w < kV);
      #pragma unroll
      for (int i = 0; i < 4; ++i) {
        const int mt = wid * 4 + i;
        f32x4 c0 = {0.f, 0.f, 0.f, 0.f};
        c0 = __builtin_amdgcn_mfma_f32_16x16x32_bf16(af[i], bf, c0, 0, 0, 0);
        if (wok) {
          const int mb = 16 * mt + 4 * h;
          const int cw_ = mb >> 3, dl0 = mb & 7;
          #pragma unroll
          for (int r = 0; r < 4; ++r)
            sBuf[((dl0 + r) * kV + w) * 72 + cw_] = f2b(c0[r]);
        }
      }
    }
    __syncthreads();
    #pragma unroll
    for (int ksl = 0; ksl < 2; ++ksl) {
      bf16x8 wf = *(const bf16x8*)&wsu[((mt2 * 6 + p * 2 + ksl) * 64 + lam) * 8];
      #pragma unroll
      for (int nt = 0; nt < 7; ++nt) {
        if (nh == 0 || nt < 6) {
          bf16x8 yf = *(const bf16x8*)&sBuf[(16 * (ntb + nt) + r16) * 72 + 32 * ksl + 8 * h];
          acc[nt] = __builtin_amdgcn_mfma_f32_16x16x32_bf16(wf, yf, acc[nt], 0, 0, 0);
        }
      }
    }
    if (p < 2) __syncthreads();
  }

  const int cb4 = 16 * mt2 + 4 * h;
  #pragma unroll
  for (int nt = 0; nt < 7; ++nt) {
    if (nh == 0 || nt < 6) {
      int nidx = 16 * (ntb + nt) + r16;
      if (nidx < 200) {
        int dl = nidx / 25, wv = nidx - 25 * dl;
        float cnt = l0 ? 9.f : (float)(dl + 1);
        long base = (long)(l0 + dl) * kV + wv;
        #pragma unroll
        for (int r = 0; r < 4; ++r) {
          int c = cb4 + r;
          float val = acc[nt][r] + cnt * bias2[c * kV + wv] + xn[(long)c * kXsC + base];
          outn[(long)c * kXsC + base] = fmaxf(val, 0.f);
        }
      }
    }
  }
}

extern "C" void kernel_launch(void* const* d_in, const int* in_sizes, int n_in,
                              void* d_out, int out_size, void* d_ws, size_t ws_size,
                              hipStream_t stream) {
  const float* x  = (const float*)d_in[0];
  const float* A  = (const float*)d_in[1];
  const float* cw = (const float*)d_in[2];
  const float* cb = (const float*)d_in[3];
  float* outp = (float*)d_out;

  if (ws_size >= kWOffB + kWBytes) {
    unsigned short* sxg = (unsigned short*)d_ws;
    unsigned short* wsu = (unsigned short*)((char*)d_ws + kWOffB);
    hipLaunchKernelGGL(stgcn_pre, dim3(1), dim3(256), 0, stream, A, cw, cb, wsu);
    hipLaunchKernelGGL(stgcn_winsum, dim3(16 * 64), dim3(256), 0, stream, x, sxg);
    hipLaunchKernelGGL(stgcn_mm, dim3(kL / kTL, 16), dim3(512), 0, stream,
                       x, sxg, wsu, outp);
  } else {
    unsigned short* wsu = (unsigned short*)d_ws;   // needs 37120 B
    hipLaunchKernelGGL(stgcn_pre, dim3(1), dim3(256), 0, stream, A, cw, cb, wsu);
    hipLaunchKernelGGL(stgcn_fused, dim3(kL / kTL, 16), dim3(512), 0, stream,
                       x, wsu, outp);
  }
}

// Round 7
// 302.185 us; speedup vs baseline: 1.6126x; 1.6126x over previous
//
#include <hip/hip_runtime.h>

namespace {
constexpr int kL    = 2048;
constexpr int kV    = 25;
constexpr int kTL   = 8;
constexpr int kXsC  = kL * kV;          // 51200
constexpr long kXsN = 64L * kXsC;

typedef __attribute__((ext_vector_type(8)))  short bf16x8;
typedef __attribute__((ext_vector_type(16))) float f32x16;
typedef __attribute__((ext_vector_type(4)))  unsigned short us4;

__device__ __forceinline__ unsigned short f2b(float f) {
  union { float f; unsigned u; } x; x.f = f;
  unsigned r = x.u + 0x7FFF + ((x.u >> 16) & 1);
  return (unsigned short)(r >> 16);
}
}

// ws layout (ushort):
//  [0, 12288)      S2 A-frags bf16[2 mt2][12 kg][64 lane][8]  (W[c][k=p*64+ci], 32x32x16 A-layout)
//  [12288, 15360)  S1 B-frags bf16[3 p][2 ks][64 lane][8]     (A[p][v][w] 0-pad, 32x32x16 B-layout)
//  byte 30720      bias2 fp32[64][25]
__global__ void stgcn_pre(const float* __restrict__ A,
                          const float* __restrict__ cw,
                          const float* __restrict__ cb,
                          unsigned short* __restrict__ wsu) {
  int t = threadIdx.x;
  for (int i = t; i < 2 * 12 * 64 * 8; i += 256) {
    int j = i & 7, lane = (i >> 3) & 63;
    int rem = i >> 9;                 // 0..23
    int kg = rem % 12, mt2 = rem / 12;
    int c  = 32 * mt2 + (lane & 31);
    int p  = kg >> 2, ksl = kg & 3;
    int ci = 16 * ksl + 8 * (lane >> 5) + j;
    wsu[i] = f2b(cw[(p * 64 + c) * 64 + ci]);
  }
  for (int i = t; i < 3 * 2 * 64 * 8; i += 256) {
    int j = i & 7, lane = (i >> 3) & 63, ks = (i >> 9) & 1, p = i >> 10;
    int w = lane & 31;
    int v = 16 * ks + 8 * (lane >> 5) + j;
    float val = (v < kV && w < kV) ? A[(p * kV + v) * kV + w] : 0.f;
    wsu[12288 + i] = f2b(val);
  }
  float* bias2 = (float*)((char*)wsu + 30720);
  for (int i = t; i < 64 * kV; i += 256) {
    int c = i / kV, w = i % kV;
    float s = 0.f;
    for (int p = 0; p < 3; ++p) {
      float as = 0.f;
      for (int v = 0; v < kV; ++v) as += A[(p * kV + v) * kV + w];
      s += cb[p * 64 + c] * as;
    }
    bias2[i] = s;
  }
}

__global__ __launch_bounds__(512, 4)
void stgcn_main(const float* __restrict__ x,
                const unsigned short* __restrict__ wsu,
                float* __restrict__ out) {
  // Unioned LDS (57344 B -> 2 blocks/CU):
  //  Phase A/B: SX bf16 [m=ci*8+dl][40]  (20480 us; 8-us blocks XOR'd by ci&3) -- R5 layout
  //  p-loop:    sYs bf16 [2 buf][nidx 224][ci 64], octet o stored at o^(nidx&7)
  __shared__ unsigned short sBuf[2 * 224 * 64];   // 28672 us

  const int t    = threadIdx.x;
  const int lane = t & 63;
  const int wid  = t >> 6;            // 0..7
  const int hi   = lane >> 5;         // 0..1
  const int l31  = lane & 31;
  const int l0   = blockIdx.x * kTL;
  const float* xn = x + (long)blockIdx.y * kXsN;
  float* outn     = out + (long)blockIdx.y * kXsN;
  const float* bias2 = (const float*)((const char*)wsu + 30720);

  // ---- Phase A: rolling window sums, global -> regs -> LDS (R5 verbatim) ----
  {
    const int ci = t >> 3, q = t & 7;
    const int rowb = ci * 8 * 40;
    if (q == 7) {
      const int c4 = ((3 ^ (ci & 3)) << 3) | 4;   // logical cols 28..31
      us4 z = {0, 0, 0, 0};
      #pragma unroll
      for (int dl = 0; dl < 8; ++dl) *(us4*)&sBuf[rowb + dl * 40 + c4] = z;
    } else {
      const int colL = 4 * q;
      const int c4 = (((colL >> 3) ^ (ci & 3)) << 3) | (colL & 7);
      const float* xr = xn + (long)ci * kXsC + (long)(l0 - 8) * kV + colL;
      const bool full = (q < 6);                  // q==6 -> only v=24 valid
      float a0 = 0.f, a1 = 0.f, a2 = 0.f, a3 = 0.f;
      if (l0) {
        #pragma unroll
        for (int j = 0; j < 9; ++j) {
          const float* r = xr + j * kV;
          a0 += r[0];
          if (full) { a1 += r[1]; a2 += r[2]; a3 += r[3]; }
        }
      } else {
        const float* r = xr + 8 * kV;
        a0 = r[0];
        if (full) { a1 = r[1]; a2 = r[2]; a3 = r[3]; }
      }
      #pragma unroll
      for (int dl = 0; dl < 8; ++dl) {
        us4 o = { f2b(a0), f2b(a1), f2b(a2), f2b(a3) };
        *(us4*)&sBuf[rowb + dl * 40 + c4] = o;
        if (dl < 7) {
          const float* pn = xr + (dl + 9) * kV;
          a0 += pn[0];
          if (full) { a1 += pn[1]; a2 += pn[2]; a3 += pn[3]; }
          if (l0) {
            const float* po = xr + dl * kV;
            a0 -= po[0];
            if (full) { a1 -= po[1]; a2 -= po[2]; a3 -= po[3]; }
          }
        }
      }
    }
  }
  __syncthreads();   // bar1

  // ---- Phase B: hoist A-fragments (p-invariant) + residual preload ----
  bf16x8 af[2][2];
  #pragma unroll
  for (int mtl = 0; mtl < 2; ++mtl) {
    const int m  = 32 * (2 * wid + mtl) + l31;
    const int cia = m >> 3;
    #pragma unroll
    for (int ks = 0; ks < 2; ++ks) {
      const int vblk = 2 * ks + hi;
      af[mtl][ks] = *(const bf16x8*)&sBuf[m * 40 + ((vblk ^ (cia & 3)) << 3)];
    }
  }

  const int mt2 = wid & 1;
  const int ng  = wid >> 1;
  const int nnt = (ng < 3) ? 2 : 1;
  const int nt0 = (ng < 3) ? 2 * ng : 6;

  float res[2][16];
  #pragma unroll
  for (int q = 0; q < 2; ++q) {
    if (q < nnt) {
      const int nidx = 32 * (nt0 + q) + l31;
      const bool ok = nidx < 200;
      const int dl = ok ? nidx / 25 : 0;
      const int wv = ok ? nidx - 25 * (nidx / 25) : 0;
      const long base = (long)(l0 + dl) * kV + wv;
      #pragma unroll
      for (int r = 0; r < 16; ++r) {
        const int c = 32 * mt2 + (r & 3) + 8 * (r >> 2) + 4 * hi;
        res[q][r] = ok ? xn[(long)c * kXsC + base] : 0.f;
      }
    }
  }
  __syncthreads();   // bar2 -- SX dead, sBuf becomes sYs[2][224][64]

  // zero pad rows 200..223 of both buffers (nidx >= 200 never written by S1)
  for (int i = t; i < 1536; i += 512) {
    sBuf[12800 + i] = 0;            // buf0 rows 200..223
    sBuf[14336 + 12800 + i] = 0;    // buf1 rows 200..223
  }

  f32x16 acc[2];
  #pragma unroll
  for (int q = 0; q < 2; ++q)
    #pragma unroll
    for (int r = 0; r < 16; ++r) acc[q][r] = 0.f;

  const bool wok = (l31 < kV);

  // ---- S1: Y_p[(ci,dl)][w] -> sYs[buf] ----
  #define S1(p, buf) {                                                        \
    _Pragma("unroll")                                                         \
    for (int mtl = 0; mtl < 2; ++mtl) {                                       \
      f32x16 cz;                                                              \
      _Pragma("unroll")                                                       \
      for (int r = 0; r < 16; ++r) cz[r] = 0.f;                               \
      _Pragma("unroll")                                                       \
      for (int ks = 0; ks < 2; ++ks) {                                        \
        bf16x8 bfr = *(const bf16x8*)&wsu[12288 + (((p) * 2 + ks) * 64 + lane) * 8]; \
        cz = __builtin_amdgcn_mfma_f32_32x32x16_bf16(af[mtl][ks], bfr, cz, 0, 0, 0); \
      }                                                                       \
      if (wok) {                                                              \
        _Pragma("unroll")                                                     \
        for (int r = 0; r < 16; ++r) {                                        \
          const int mo = (r & 3) + 8 * (r >> 2) + 4 * hi;                     \
          const int m  = 32 * (2 * wid + mtl) + mo;                           \
          const int ci = m >> 3;                                              \
          const int nidx = (m & 7) * kV + l31;                                \
          sBuf[(buf) * 14336 + nidx * 64 + (((ci >> 3) ^ (nidx & 7)) << 3) + (ci & 7)] = f2b(cz[r]); \
        }                                                                     \
      }                                                                       \
    }                                                                         \
  }

  // ---- S2: acc += W_p^T Y_p ----
  #define S2(p, buf) {                                                        \
    _Pragma("unroll")                                                         \
    for (int ksl = 0; ksl < 4; ++ksl) {                                       \
      bf16x8 wf = *(const bf16x8*)&wsu[((mt2 * 12 + (p) * 4 + ksl) * 64 + lane) * 8]; \
      _Pragma("unroll")                                                       \
      for (int q = 0; q < 2; ++q) {                                           \
        if (q < nnt) {                                                        \
          const int nidx = 32 * (nt0 + q) + l31;                              \
          const int o = 2 * ksl + hi;                                         \
          bf16x8 yf = *(const bf16x8*)&sBuf[(buf) * 14336 + nidx * 64 + ((o ^ (nidx & 7)) << 3)]; \
          acc[q] = __builtin_amdgcn_mfma_f32_32x32x16_bf16(wf, yf, acc[q], 0, 0, 0); \
        }                                                                     \
      }                                                                       \
    }                                                                         \
  }

  S1(0, 0);
  __syncthreads();   // bar3
  S2(0, 0); S1(1, 1);
  __syncthreads();   // bar4
  S2(1, 1); S1(2, 0);
  __syncthreads();   // bar5
  S2(2, 0);

  #undef S1
  #undef S2

  // ---- Epilogue: + cnt*bias2 + residual (preloaded), ReLU, store ----
  #pragma unroll
  for (int q = 0; q < 2; ++q) {
    if (q < nnt) {
      const int nidx = 32 * (nt0 + q) + l31;
      if (nidx < 200) {
        const int dl = nidx / 25, wv = nidx - 25 * (nidx / 25);
        const float cnt = l0 ? 9.f : (float)(dl + 1);
        const long base = (long)(l0 + dl) * kV + wv;
        #pragma unroll
        for (int r = 0; r < 16; ++r) {
          const int c = 32 * mt2 + (r & 3) + 8 * (r >> 2) + 4 * hi;
          float val = acc[q][r] + cnt * bias2[c * kV + wv] + res[q][r];
          outn[(long)c * kXsC + base] = fmaxf(val, 0.f);
        }
      }
    }
  }
}

extern "C" void kernel_launch(void* const* d_in, const int* in_sizes, int n_in,
                              void* d_out, int out_size, void* d_ws, size_t ws_size,
                              hipStream_t stream) {
  const float* x  = (const float*)d_in[0];
  const float* A  = (const float*)d_in[1];
  const float* cw = (const float*)d_in[2];
  const float* cb = (const float*)d_in[3];
  unsigned short* wsu = (unsigned short*)d_ws;   // needs 37120 B

  hipLaunchKernelGGL(stgcn_pre, dim3(1), dim3(256), 0, stream, A, cw, cb, wsu);
  hipLaunchKernelGGL(stgcn_main, dim3(kL / kTL, 16), dim3(512), 0, stream,
                     x, wsu, (float*)d_out);
}

// Round 8
// 256.252 us; speedup vs baseline: 1.9017x; 1.1793x over previous
//
#include <hip/hip_runtime.h>

namespace {
constexpr int kL    = 2048;
constexpr int kV    = 25;
constexpr int kTL   = 8;
constexpr int kXsC  = kL * kV;          // 51200
constexpr long kXsN = 64L * kXsC;

typedef __attribute__((ext_vector_type(8)))  short bf16x8;
typedef __attribute__((ext_vector_type(16))) float f32x16;
typedef __attribute__((ext_vector_type(4)))  unsigned short us4;

__device__ __forceinline__ float b2f(unsigned short u) {
  union { unsigned u32; float f; } x; x.u32 = ((unsigned)u) << 16; return x.f;
}
__device__ __forceinline__ unsigned short f2b(float f) {
  union { float f; unsigned u; } x; x.f = f;
  unsigned r = x.u + 0x7FFF + ((x.u >> 16) & 1);
  return (unsigned short)(r >> 16);
}
}

// ws layout (ushort):
//  [0, 12288)      S2 A-frags bf16[2 mt2][12 kg][64 lane][8]  (W[c][k=p*64+ci], 32x32x16 A-layout)
//  [12288, 15360)  S1 B-frags bf16[3 p][2 ks][64 lane][8]     (A[p][v][w] 0-pad, 32x32x16 B-layout)
//  byte 30720      bias2 fp32[64][25]
__global__ void stgcn_pre(const float* __restrict__ A,
                          const float* __restrict__ cw,
                          const float* __restrict__ cb,
                          unsigned short* __restrict__ wsu) {
  int tid = blockIdx.x * 256 + threadIdx.x;
  int nthr = gridDim.x * 256;
  for (int i = tid; i < 2 * 12 * 64 * 8; i += nthr) {
    int j = i & 7, lane = (i >> 3) & 63;
    int rem = i >> 9;                 // 0..23
    int kg = rem % 12, mt2 = rem / 12;
    int c  = 32 * mt2 + (lane & 31);
    int p  = kg >> 2, ksl = kg & 3;
    int ci = 16 * ksl + 8 * (lane >> 5) + j;
    wsu[i] = f2b(cw[(p * 64 + c) * 64 + ci]);
  }
  for (int i = tid; i < 3 * 2 * 64 * 8; i += nthr) {
    int j = i & 7, lane = (i >> 3) & 63, ks = (i >> 9) & 1, p = i >> 10;
    int w = lane & 31;
    int v = 16 * ks + 8 * (lane >> 5) + j;
    float val = (v < kV && w < kV) ? A[(p * kV + v) * kV + w] : 0.f;
    wsu[12288 + i] = f2b(val);
  }
  float* bias2 = (float*)((char*)wsu + 30720);
  for (int i = tid; i < 64 * kV; i += nthr) {
    int c = i / kV, w = i % kV;
    float s = 0.f;
    for (int p = 0; p < 3; ++p) {
      float as = 0.f;
      for (int v = 0; v < kV; ++v) as += A[(p * kV + v) * kV + w];
      s += cb[p * 64 + c] * as;
    }
    bias2[i] = s;
  }
}

__global__ __launch_bounds__(512, 4)
void stgcn_main(const float* __restrict__ x,
                const unsigned short* __restrict__ wsu,
                float* __restrict__ out) {
  // Unioned LDS (69632 B -> 2 blocks/CU):
  //  [0,20480)      Phase A/B: SX bf16 [m=ci*8+dl][40] (8-us blocks XOR'd by ci&3)
  //                 p-loop:    sYs bf16 [nidx 224][64] (octet o at o^(nidx&7)), single buffer
  //  [20480,34816)  sRes bf16 [ci][dl][28] -- residual x slice, stashed during Phase A
  __shared__ unsigned short sBuf[34816];

  const int t    = threadIdx.x;
  const int lane = t & 63;
  const int wid  = t >> 6;            // 0..7
  const int hi   = lane >> 5;         // 0..1
  const int l31  = lane & 31;
  const int l0   = blockIdx.x * kTL;
  const float* xn = x + (long)blockIdx.y * kXsN;
  float* outn     = out + (long)blockIdx.y * kXsN;
  const float* bias2 = (const float*)((const char*)wsu + 30720);
  unsigned short* sRes = sBuf + 20480;

  // ---- Phase A: rolling window sums + residual stash ----
  {
    const int ci = t >> 3, q = t & 7;
    const int rowb = ci * 8 * 40;
    if (q == 7) {
      const int c4 = ((3 ^ (ci & 3)) << 3) | 4;   // logical cols 28..31
      us4 z = {0, 0, 0, 0};
      #pragma unroll
      for (int dl = 0; dl < 8; ++dl) *(us4*)&sBuf[rowb + dl * 40 + c4] = z;
    } else {
      const int colL = 4 * q;
      const int c4 = (((colL >> 3) ^ (ci & 3)) << 3) | (colL & 7);
      const float* xr = xn + (long)ci * kXsC + (long)(l0 - 8) * kV + colL;
      const int resb = ci * 8 * 28 + colL;
      const bool full = (q < 6);                  // q==6 -> only v=24 valid
      float a0 = 0.f, a1 = 0.f, a2 = 0.f, a3 = 0.f;
      if (l0) {
        #pragma unroll
        for (int j = 0; j < 8; ++j) {
          const float* r = xr + j * kV;
          a0 += r[0];
          if (full) { a1 += r[1]; a2 += r[2]; a3 += r[3]; }
        }
      }
      {
        const float* r = xr + 8 * kV;             // row l0 (d = 0)
        float x0 = r[0], x1 = full ? r[1] : 0.f, x2 = full ? r[2] : 0.f, x3 = full ? r[3] : 0.f;
        a0 += x0; a1 += x1; a2 += x2; a3 += x3;
        us4 rs = { f2b(x0), f2b(x1), f2b(x2), f2b(x3) };
        *(us4*)&sRes[resb] = rs;
      }
      #pragma unroll
      for (int dl = 0; dl < 8; ++dl) {
        us4 o = { f2b(a0), f2b(a1), f2b(a2), f2b(a3) };
        *(us4*)&sBuf[rowb + dl * 40 + c4] = o;
        if (dl < 7) {
          const float* pn = xr + (dl + 9) * kV;   // row l0+dl+1 (d = dl+1)
          float x0 = pn[0], x1 = full ? pn[1] : 0.f, x2 = full ? pn[2] : 0.f, x3 = full ? pn[3] : 0.f;
          us4 rs = { f2b(x0), f2b(x1), f2b(x2), f2b(x3) };
          *(us4*)&sRes[resb + (dl + 1) * 28] = rs;
          a0 += x0; a1 += x1; a2 += x2; a3 += x3;
          if (l0) {
            const float* po = xr + dl * kV;
            a0 -= po[0];
            if (full) { a1 -= po[1]; a2 -= po[2]; a3 -= po[3]; }
          }
        }
      }
    }
  }
  __syncthreads();   // bar1

  // ---- Phase B: hoist A-fragments (p-invariant) ----
  bf16x8 af[2][2];
  #pragma unroll
  for (int mtl = 0; mtl < 2; ++mtl) {
    const int m  = 32 * (2 * wid + mtl) + l31;
    const int cia = m >> 3;
    #pragma unroll
    for (int ks = 0; ks < 2; ++ks) {
      const int vblk = 2 * ks + hi;
      af[mtl][ks] = *(const bf16x8*)&sBuf[m * 40 + ((vblk ^ (cia & 3)) << 3)];
    }
  }
  __syncthreads();   // bar2 -- SX dead, sBuf[0,14336) becomes sYs[224][64]

  // zero sYs pad rows 200..223 (never written by S1)
  for (int i = t; i < 1536; i += 512) sBuf[12800 + i] = 0;

  const int mt2 = wid & 1;
  const int ng  = wid >> 1;
  const int nnt = (ng < 3) ? 2 : 1;
  const int nt0 = (ng < 3) ? 2 * ng : 6;

  f32x16 acc[2];
  #pragma unroll
  for (int q = 0; q < 2; ++q)
    #pragma unroll
    for (int r = 0; r < 16; ++r) acc[q][r] = 0.f;

  const bool wok = (l31 < kV);

  // ---- S1: Y_p[(ci,dl)][w] -> sYs ----
  #define S1(p) {                                                             \
    _Pragma("unroll")                                                         \
    for (int mtl = 0; mtl < 2; ++mtl) {                                       \
      f32x16 cz;                                                              \
      _Pragma("unroll")                                                       \
      for (int r = 0; r < 16; ++r) cz[r] = 0.f;                               \
      _Pragma("unroll")                                                       \
      for (int ks = 0; ks < 2; ++ks) {                                        \
        bf16x8 bfr = *(const bf16x8*)&wsu[12288 + (((p) * 2 + ks) * 64 + lane) * 8]; \
        cz = __builtin_amdgcn_mfma_f32_32x32x16_bf16(af[mtl][ks], bfr, cz, 0, 0, 0); \
      }                                                                       \
      if (wok) {                                                              \
        _Pragma("unroll")                                                     \
        for (int r = 0; r < 16; ++r) {                                        \
          const int mo = (r & 3) + 8 * (r >> 2) + 4 * hi;                     \
          const int m  = 32 * (2 * wid + mtl) + mo;                           \
          const int ci = m >> 3;                                              \
          const int nidx = (m & 7) * kV + l31;                                \
          sBuf[nidx * 64 + (((ci >> 3) ^ (nidx & 7)) << 3) + (ci & 7)] = f2b(cz[r]); \
        }                                                                     \
      }                                                                       \
    }                                                                         \
  }

  // ---- S2: acc += W_p^T Y_p ----
  #define S2(p) {                                                             \
    _Pragma("unroll")                                                         \
    for (int ksl = 0; ksl < 4; ++ksl) {                                       \
      bf16x8 wf = *(const bf16x8*)&wsu[((mt2 * 12 + (p) * 4 + ksl) * 64 + lane) * 8]; \
      _Pragma("unroll")                                                       \
      for (int q = 0; q < 2; ++q) {                                           \
        if (q < nnt) {                                                        \
          const int nidx = 32 * (nt0 + q) + l31;                              \
          const int o = 2 * ksl + hi;                                         \
          bf16x8 yf = *(const bf16x8*)&sBuf[nidx * 64 + ((o ^ (nidx & 7)) << 3)]; \
          acc[q] = __builtin_amdgcn_mfma_f32_32x32x16_bf16(wf, yf, acc[q], 0, 0, 0); \
        }                                                                     \
      }                                                                       \
    }                                                                         \
  }

  S1(0); __syncthreads();
  S2(0); __syncthreads();
  S1(1); __syncthreads();
  S2(1); __syncthreads();
  S1(2); __syncthreads();
  S2(2);

  #undef S1
  #undef S2

  // ---- Epilogue: + cnt*bias2 + residual (from LDS), ReLU, store ----
  #pragma unroll
  for (int q = 0; q < 2; ++q) {
    if (q < nnt) {
      const int nidx = 32 * (nt0 + q) + l31;
      if (nidx < 200) {
        const int dl = nidx / 25, wv = nidx - 25 * (nidx / 25);
        const float cnt = l0 ? 9.f : (float)(dl + 1);
        const long base = (long)(l0 + dl) * kV + wv;
        #pragma unroll
        for (int r = 0; r < 16; ++r) {
          const int c = 32 * mt2 + (r & 3) + 8 * (r >> 2) + 4 * hi;
          float val = acc[q][r] + cnt * bias2[c * kV + wv]
                    + b2f(sRes[(c * 8 + dl) * 28 + wv]);
          outn[(long)c * kXsC + base] = fmaxf(val, 0.f);
        }
      }
    }
  }
}

extern "C" void kernel_launch(void* const* d_in, const int* in_sizes, int n_in,
                              void* d_out, int out_size, void* d_ws, size_t ws_size,
                              hipStream_t stream) {
  const float* x  = (const float*)d_in[0];
  const float* A  = (const float*)d_in[1];
  const float* cw = (const float*)d_in[2];
  const float* cb = (const float*)d_in[3];
  unsigned short* wsu = (unsigned short*)d_ws;   // needs 37120 B

  hipLaunchKernelGGL(stgcn_pre, dim3(8), dim3(256), 0, stream, A, cw, cb, wsu);
  hipLaunchKernelGGL(stgcn_main, dim3(kL / kTL, 16), dim3(512), 0, stream,
                     x, wsu, (float*)d_out);
}

// Round 9
// 238.317 us; speedup vs baseline: 2.0448x; 1.0753x over previous
//
#include <hip/hip_runtime.h>

namespace {
constexpr int kL    = 2048;
constexpr int kV    = 25;
constexpr int kTL   = 8;
constexpr int kXsC  = kL * kV;          // 51200
constexpr long kXsN = 64L * kXsC;

typedef __attribute__((ext_vector_type(8)))  short bf16x8;
typedef __attribute__((ext_vector_type(16))) float f32x16;
typedef __attribute__((ext_vector_type(4)))  unsigned short us4;

__device__ __forceinline__ float b2f(unsigned short u) {
  union { unsigned u32; float f; } x; x.u32 = ((unsigned)u) << 16; return x.f;
}
__device__ __forceinline__ unsigned short f2b(float f) {
  union { float f; unsigned u; } x; x.f = f;
  unsigned r = x.u + 0x7FFF + ((x.u >> 16) & 1);
  return (unsigned short)(r >> 16);
}
__device__ __forceinline__ unsigned cvt_pk(float lo, float hi) {
  unsigned r;
  asm("v_cvt_pk_bf16_f32 %0, %1, %2" : "=v"(r) : "v"(lo), "v"(hi));
  return r;
}
}

// ws layout (ushort):
//  [0, 12288)      S2 A-frags bf16[2 mt2][12 kg][64 lane][8]  (W[c][k=p*64+ci], 32x32x16 A-layout)
//  [12288, 15360)  S1 B-frags bf16[3 p][2 ks][64 lane][8]     (A[p][v][w] 0-pad, 32x32x16 B-layout)
//  byte 30720      bias2 fp32[64][25]
__global__ void stgcn_pre(const float* __restrict__ A,
                          const float* __restrict__ cw,
                          const float* __restrict__ cb,
                          unsigned short* __restrict__ wsu) {
  int tid = blockIdx.x * 256 + threadIdx.x;
  int nthr = gridDim.x * 256;
  for (int i = tid; i < 2 * 12 * 64 * 8; i += nthr) {
    int j = i & 7, lane = (i >> 3) & 63;
    int rem = i >> 9;                 // 0..23
    int kg = rem % 12, mt2 = rem / 12;
    int c  = 32 * mt2 + (lane & 31);
    int p  = kg >> 2, ksl = kg & 3;
    int ci = 16 * ksl + 8 * (lane >> 5) + j;
    wsu[i] = f2b(cw[(p * 64 + c) * 64 + ci]);
  }
  for (int i = tid; i < 3 * 2 * 64 * 8; i += nthr) {
    int j = i & 7, lane = (i >> 3) & 63, ks = (i >> 9) & 1, p = i >> 10;
    int w = lane & 31;
    int v = 16 * ks + 8 * (lane >> 5) + j;
    float val = (v < kV && w < kV) ? A[(p * kV + v) * kV + w] : 0.f;
    wsu[12288 + i] = f2b(val);
  }
  float* bias2 = (float*)((char*)wsu + 30720);
  for (int i = tid; i < 64 * kV; i += nthr) {
    int c = i / kV, w = i % kV;
    float s = 0.f;
    for (int p = 0; p < 3; ++p) {
      float as = 0.f;
      for (int v = 0; v < kV; ++v) as += A[(p * kV + v) * kV + w];
      s += cb[p * 64 + c] * as;
    }
    bias2[i] = s;
  }
}

__global__ __launch_bounds__(512, 4)
void stgcn_main(const float* __restrict__ x,
                const unsigned short* __restrict__ wsu,
                float* __restrict__ out) {
  // Unioned LDS (69632 B -> 2 blocks/CU):
  //  [0,20480)      Phase A/B: SX bf16 [m=ci*8+dl][40] (8-us blocks XOR'd by ci&3)
  //                 p-loop:    sYs bf16 [nidx 224][64] (octet o at o^(nidx&7)), single buffer
  //  [20480,34816)  sRes bf16 [ci][dl][28] -- residual x slice, stashed during Phase A
  __shared__ unsigned short sBuf[34816];

  const int t    = threadIdx.x;
  const int lane = t & 63;
  const int wid  = t >> 6;            // 0..7
  const int hi   = lane >> 5;         // 0..1
  const int l31  = lane & 31;

  // XCD-aware bijective swizzle (nwg=4096, 8 XCDs): each XCD gets contiguous
  // l-tiles of one n -> output tile-boundary lines + x window overlap stay in
  // that XCD's L2 instead of being split/double-written across XCDs.
  const int b   = blockIdx.x + (int)gridDim.x * blockIdx.y;   // 0..4095
  const int w_  = (b & 7) * 512 + (b >> 3);
  const int lt  = w_ & 255;
  const int nb  = w_ >> 8;
  const int l0  = lt * kTL;

  const float* xn = x + (long)nb * kXsN;
  float* outn     = out + (long)nb * kXsN;
  const float* bias2 = (const float*)((const char*)wsu + 30720);
  unsigned short* sRes = sBuf + 20480;

  // ---- Phase A: rolling window sums + residual stash ----
  {
    const int ci = t >> 3, q = t & 7;
    const int rowb = ci * 8 * 40;
    if (q == 7) {
      const int c4 = ((3 ^ (ci & 3)) << 3) | 4;   // logical cols 28..31
      uint2 z = {0u, 0u};
      #pragma unroll
      for (int dl = 0; dl < 8; ++dl) *(uint2*)&sBuf[rowb + dl * 40 + c4] = z;
    } else {
      const int colL = 4 * q;
      const int c4 = (((colL >> 3) ^ (ci & 3)) << 3) | (colL & 7);
      const float* xr = xn + (long)ci * kXsC + (long)(l0 - 8) * kV + colL;
      const int resb = ci * 8 * 28 + colL;
      const bool full = (q < 6);                  // q==6 -> only v=24 valid
      float a0 = 0.f, a1 = 0.f, a2 = 0.f, a3 = 0.f;
      if (l0) {
        #pragma unroll
        for (int j = 0; j < 8; ++j) {
          const float* r = xr + j * kV;
          a0 += r[0];
          if (full) { a1 += r[1]; a2 += r[2]; a3 += r[3]; }
        }
      }
      {
        const float* r = xr + 8 * kV;             // row l0 (d = 0)
        float x0 = r[0], x1 = full ? r[1] : 0.f, x2 = full ? r[2] : 0.f, x3 = full ? r[3] : 0.f;
        a0 += x0; a1 += x1; a2 += x2; a3 += x3;
        uint2 rs = { cvt_pk(x0, x1), cvt_pk(x2, x3) };
        *(uint2*)&sRes[resb] = rs;
      }
      #pragma unroll
      for (int dl = 0; dl < 8; ++dl) {
        uint2 o = { cvt_pk(a0, a1), cvt_pk(a2, a3) };
        *(uint2*)&sBuf[rowb + dl * 40 + c4] = o;
        if (dl < 7) {
          const float* pn = xr + (dl + 9) * kV;   // row l0+dl+1 (d = dl+1)
          float x0 = pn[0], x1 = full ? pn[1] : 0.f, x2 = full ? pn[2] : 0.f, x3 = full ? pn[3] : 0.f;
          uint2 rs = { cvt_pk(x0, x1), cvt_pk(x2, x3) };
          *(uint2*)&sRes[resb + (dl + 1) * 28] = rs;
          a0 += x0; a1 += x1; a2 += x2; a3 += x3;
          if (l0) {
            const float* po = xr + dl * kV;
            a0 -= po[0];
            if (full) { a1 -= po[1]; a2 -= po[2]; a3 -= po[3]; }
          }
        }
      }
    }
  }
  __syncthreads();   // bar1

  // ---- Phase B: hoist A-fragments (p-invariant) ----
  bf16x8 af[2][2];
  #pragma unroll
  for (int mtl = 0; mtl < 2; ++mtl) {
    const int m  = 32 * (2 * wid + mtl) + l31;
    const int cia = m >> 3;
    #pragma unroll
    for (int ks = 0; ks < 2; ++ks) {
      const int vblk = 2 * ks + hi;
      af[mtl][ks] = *(const bf16x8*)&sBuf[m * 40 + ((vblk ^ (cia & 3)) << 3)];
    }
  }
  __syncthreads();   // bar2 -- SX dead, sBuf[0,14336) becomes sYs[224][64]

  // NOTE: sYs rows 200..223 are never written (S1 writes nidx<=199 only) and
  // may hold stale SX garbage. Safe: in S2, Y is the B-operand, so row nidx
  // only feeds D *column* nidx (per-column independence) -- columns >=200 are
  // discarded at the store. No zero-init needed.

  const int mt2 = wid & 1;
  const int ng  = wid >> 1;
  const int nnt = (ng < 3) ? 2 : 1;
  const int nt0 = (ng < 3) ? 2 * ng : 6;

  f32x16 acc[2];
  #pragma unroll
  for (int q = 0; q < 2; ++q)
    #pragma unroll
    for (int r = 0; r < 16; ++r) acc[q][r] = 0.f;

  const bool wok = (l31 < kV);

  // ---- S1: Y_p[(ci,dl)][w] -> sYs ----
  #define S1(p) {                                                             \
    _Pragma("unroll")                                                         \
    for (int mtl = 0; mtl < 2; ++mtl) {                                       \
      f32x16 cz;                                                              \
      _Pragma("unroll")                                                       \
      for (int r = 0; r < 16; ++r) cz[r] = 0.f;                               \
      _Pragma("unroll")                                                       \
      for (int ks = 0; ks < 2; ++ks) {                                        \
        bf16x8 bfr = *(const bf16x8*)&wsu[12288 + (((p) * 2 + ks) * 64 + lane) * 8]; \
        cz = __builtin_amdgcn_mfma_f32_32x32x16_bf16(af[mtl][ks], bfr, cz, 0, 0, 0); \
      }                                                                       \
      if (wok) {                                                              \
        _Pragma("unroll")                                                     \
        for (int r = 0; r < 16; ++r) {                                        \
          const int mo = (r & 3) + 8 * (r >> 2) + 4 * hi;                     \
          const int m  = 32 * (2 * wid + mtl) + mo;                           \
          const int ci = m >> 3;                                              \
          const int nidx = (m & 7) * kV + l31;                                \
          sBuf[nidx * 64 + (((ci >> 3) ^ (nidx & 7)) << 3) + (ci & 7)] =      \
              (unsigned short)cvt_pk(cz[r], cz[r]);                           \
        }                                                                     \
      }                                                                       \
    }                                                                         \
  }

  // ---- S2: acc += W_p^T Y_p ----
  #define S2(p) {                                                             \
    _Pragma("unroll")                                                         \
    for (int ksl = 0; ksl < 4; ++ksl) {                                       \
      bf16x8 wf = *(const bf16x8*)&wsu[((mt2 * 12 + (p) * 4 + ksl) * 64 + lane) * 8]; \
      _Pragma("unroll")                                                       \
      for (int q = 0; q < 2; ++q) {                                           \
        if (q < nnt) {                                                        \
          const int nidx = 32 * (nt0 + q) + l31;                              \
          const int o = 2 * ksl + hi;                                         \
          bf16x8 yf = *(const bf16x8*)&sBuf[nidx * 64 + ((o ^ (nidx & 7)) << 3)]; \
          acc[q] = __builtin_amdgcn_mfma_f32_32x32x16_bf16(wf, yf, acc[q], 0, 0, 0); \
        }                                                                     \
      }                                                                       \
    }                                                                         \
  }

  S1(0); __syncthreads();
  S2(0); __syncthreads();
  S1(1); __syncthreads();
  S2(1); __syncthreads();
  S1(2); __syncthreads();
  S2(2);

  #undef S1
  #undef S2

  // ---- Epilogue: + cnt*bias2 + residual (from LDS), ReLU, store ----
  #pragma unroll
  for (int q = 0; q < 2; ++q) {
    if (q < nnt) {
      const int nidx = 32 * (nt0 + q) + l31;
      if (nidx < 200) {
        const int dl = nidx / 25, wv = nidx - 25 * (nidx / 25);
        const float cnt = l0 ? 9.f : (float)(dl + 1);
        const long base = (long)(l0 + dl) * kV + wv;
        #pragma unroll
        for (int r = 0; r < 16; ++r) {
          const int c = 32 * mt2 + (r & 3) + 8 * (r >> 2) + 4 * hi;
          float val = acc[q][r] + cnt * bias2[c * kV + wv]
                    + b2f(sRes[(c * 8 + dl) * 28 + wv]);
          outn[(long)c * kXsC + base] = fmaxf(val, 0.f);
        }
      }
    }
  }
}

extern "C" void kernel_launch(void* const* d_in, const int* in_sizes, int n_in,
                              void* d_out, int out_size, void* d_ws, size_t ws_size,
                              hipStream_t stream) {
  const float* x  = (const float*)d_in[0];
  const float* A  = (const float*)d_in[1];
  const float* cw = (const float*)d_in[2];
  const float* cb = (const float*)d_in[3];
  unsigned short* wsu = (unsigned short*)d_ws;   // needs 37120 B

  hipLaunchKernelGGL(stgcn_pre, dim3(8), dim3(256), 0, stream, A, cw, cb, wsu);
  hipLaunchKernelGGL(stgcn_main, dim3(kL / kTL, 16), dim3(512), 0, stream,
                     x, wsu, (float*)d_out);
}